// Round 4
// baseline (489.954 us; speedup 1.0000x reference)
//
#include <hip/hip_runtime.h>
#include <hip/hip_bf16.h>

// WindowAttention B=2048, N=64, DIM=256, 1 head, scale=1/16.
// ALGEBRAIC FUSION: proj folded into V weights (Wt = Wp@Wv, bt = Wp@bv),
// so attention PV output IS the final output (+ proj_b).
// prep (weights->bf16, Wt=Wp@Wv, bias table; ~tiny)
// -> qkv_gemm (A staged from fp32 x with in-kernel cvt; async-LDS B;
//              V~ stored PER-WINDOW transposed [win][d][64], packed 8B stores)
// -> attn (barrier-free, V~ read direct from compact 32KB/window tiles).

typedef __bf16 bf16x8_t __attribute__((ext_vector_type(8)));
typedef __bf16 bf16x4_t __attribute__((ext_vector_type(4)));
typedef float floatx4_t __attribute__((ext_vector_type(4)));

#define MFMA16(a, b, c) __builtin_amdgcn_mfma_f32_16x16x32_bf16(a, b, c, 0, 0, 0)
#define NTOK 131072  // 2048 windows * 64 tokens

__device__ __forceinline__ void gld_lds16(const void* g, void* l) {
  __builtin_amdgcn_global_load_lds(
      (const __attribute__((address_space(1))) unsigned int*)g,
      (__attribute__((address_space(3))) unsigned int*)l, 16, 0, 0);
}

__device__ __forceinline__ void cvt8(const float* src, __bf16* dst) {
  float4 f0 = reinterpret_cast<const float4*>(src)[0];
  float4 f1 = reinterpret_cast<const float4*>(src)[1];
  bf16x8_t h;
  h[0] = (__bf16)f0.x; h[1] = (__bf16)f0.y; h[2] = (__bf16)f0.z; h[3] = (__bf16)f0.w;
  h[4] = (__bf16)f1.x; h[5] = (__bf16)f1.y; h[6] = (__bf16)f1.z; h[7] = (__bf16)f1.w;
  *reinterpret_cast<bf16x8_t*>(dst) = h;
}

// ------------- prep: Wq/Wk->bf16, bias table, Wt=Wp@Wv (tiny grid) ----------
// blk <64: qkv_w rows 0-511 cvt | <80: bias table | <336: Wt row j + bt.
__global__ __launch_bounds__(256) void prep_kernel(
    const float* __restrict__ qkv_w, const float* __restrict__ qkv_b,
    const float* __restrict__ proj_w, const float* __restrict__ theta_max,
    const float* __restrict__ a_p, const float* __restrict__ b_p,
    const float* __restrict__ a_r, const float* __restrict__ b_r,
    __bf16* __restrict__ wb, float* __restrict__ bias_ws,
    float* __restrict__ btl) {
  int blk = blockIdx.x, tid = threadIdx.x;
  if (blk < 64) {
    int t = blk * 256 + tid;  // rows 0..511 of qkv_w (Q,K weights)
    cvt8(&qkv_w[(size_t)t * 8], &wb[(size_t)t * 8]);
  } else if (blk < 80) {
    int t = (blk - 64) * 256 + tid;  // 0..4095
    int i = t >> 6, j = t & 63;
    int rad = (i >> 3) - (j >> 3), az = (i & 7) - (j & 7);
    int azm = ((az % 15) + 15) % 15;
    int rdm = ((rad % 15) + 15) % 15;
    float az_ang = (float)az * 0.09817477042468103f;  // 2*pi/64
    float tm = theta_max[j >> 3];                     // broadcasts over column j
    float r_ang = (float)rad * tm * (1.0f / 64.0f);
    bias_ws[t] = a_p[azm] * cosf(az_ang) + b_p[azm] * sinf(az_ang) +
                 a_r[rdm] * cosf(r_ang) + b_r[rdm] * sinf(r_ang);
  } else {
    // Wt[j,k] = sum_d proj_w[j,d] * qkv_w[512+d, k]  (fp32, -> bf16)
    int j = blk - 80;  // 0..255
    int k = tid;
    float s = 0.f;
    for (int d = 0; d < 256; ++d)
      s += proj_w[j * 256 + d] * qkv_w[(size_t)(512 + d) * 256 + k];
    wb[(size_t)(512 + j) * 256 + k] = (__bf16)s;
    if (tid == 0) {
      float sb = 0.f;
      for (int d = 0; d < 256; ++d) sb += proj_w[j * 256 + d] * qkv_b[512 + d];
      btl[j] = sb;
    }
  }
}

// ---------------- QKV GEMM: (131072x256) @ (768x256)^T ---------------------
// A staged from fp32 x (reg-stage cvt -> swizzled ds_write_b128);
// B (bf16 weights) via async global->LDS. 128x128 tile, BK=64.
// XCD-swizzled 1D grid. Rows 512-767 of wb = Wt -> projected V~.
// V~ written PER-WINDOW transposed: Vt[win*16384 + d*64 + t] (packed 8B).
__global__ __launch_bounds__(256, 4) void qkv_gemm_kernel(
    const float* __restrict__ xf, const __bf16* __restrict__ wb,
    const float* __restrict__ qkv_b, const float* __restrict__ btl,
    __bf16* __restrict__ Qd, __bf16* __restrict__ Kd, __bf16* __restrict__ Vt) {
  __shared__ __align__(16) __bf16 aT[128 * 64];  // 16 KB, swizzled chunks
  __shared__ __align__(16) __bf16 bT[128 * 64];
  const int tid = threadIdx.x;
  const int wg = blockIdx.x;
  const int id = (wg & 7) * 768 + (wg >> 3);  // 6144 = 8 XCDs * 768
  const int bm = id / 6, bn = id - bm * 6;
  const int lane = tid & 63, wave = tid >> 6;
  const int wm = (wave >> 1) * 64, wn = (wave & 1) * 64;
  const int l15 = lane & 15, quad = lane >> 4;

  floatx4_t acc[4][4] = {};

  for (int kt = 0; kt < 4; ++kt) {
#pragma unroll
    for (int i = 0; i < 4; ++i) {
      int L = tid + i * 256;               // chunk id 0..1023
      int row = L >> 3, sc = L & 7, c8 = sc ^ (row & 7);
      gld_lds16(&wb[(size_t)(bn * 128 + row) * 256 + kt * 64 + c8 * 8], &bT[L * 8]);
      cvt8(&xf[(size_t)(bm * 128 + row) * 256 + kt * 64 + c8 * 8], &aT[L * 8]);
    }
    __syncthreads();
#pragma unroll
    for (int kc = 0; kc < 2; ++kc) {
      bf16x8_t af[4], bfr[4];
#pragma unroll
      for (int r = 0; r < 4; ++r) {
        int row = wm + r * 16 + l15, c8 = kc * 4 + quad, sc = c8 ^ (row & 7);
        af[r] = *reinterpret_cast<const bf16x8_t*>(&aT[(row * 8 + sc) * 8]);
      }
#pragma unroll
      for (int c = 0; c < 4; ++c) {
        int row = wn + c * 16 + l15, c8 = kc * 4 + quad, sc = c8 ^ (row & 7);
        bfr[c] = *reinterpret_cast<const bf16x8_t*>(&bT[(row * 8 + sc) * 8]);
      }
#pragma unroll
      for (int r = 0; r < 4; ++r)
#pragma unroll
        for (int c = 0; c < 4; ++c) acc[r][c] = MFMA16(af[r], bfr[c], acc[r][c]);
    }
    __syncthreads();
  }
  // epilogue: n<256 -> Q row-major, <512 -> K row-major, else V~ per-window T
#pragma unroll
  for (int c = 0; c < 4; ++c) {
    int n = bn * 128 + wn + c * 16 + l15;
    float bias = (n < 512) ? qkv_b[n] : btl[n - 512];
    if (n < 512) {
      __bf16* outp = (n < 256) ? Qd : Kd;
      int d = n & 255;
#pragma unroll
      for (int r = 0; r < 4; ++r) {
        int m0 = bm * 128 + wm + r * 16 + quad * 4;
#pragma unroll
        for (int g = 0; g < 4; ++g)
          outp[(size_t)(m0 + g) * 256 + d] = (__bf16)(acc[r][c][g] + bias);
      }
    } else {
      int d = n - 512;
      int w = bm * 2 + (wave >> 1);  // window id (uniform per wave)
#pragma unroll
      for (int r = 0; r < 4; ++r) {
        int t = r * 16 + quad * 4;   // token base, multiple of 4 -> 8B aligned
        bf16x4_t pk;
#pragma unroll
        for (int g = 0; g < 4; ++g) pk[g] = (__bf16)(acc[r][c][g] + bias);
        *reinterpret_cast<bf16x4_t*>(&Vt[(size_t)w * 16384 + d * 64 + t]) = pk;
      }
    }
  }
}

// ------ attention (final): barrier-free, one block per window, fp32 out -----
// Q/K row-major per window; V~ per-window transposed 32KB tile (compact).
// ldsP is wave-private (each wave writes+reads only its own 16 rows).
// out = PV~ + proj_b  (proj folded into V~ weights).
#define VPITCH 72
__global__ __launch_bounds__(256, 4) void attn_kernel(
    const __bf16* __restrict__ Qd, const __bf16* __restrict__ Kd,
    const __bf16* __restrict__ Vt, const float* __restrict__ bias_ws,
    const float* __restrict__ proj_b, float* __restrict__ out) {
  __shared__ __align__(16) __bf16 ldsP[64 * VPITCH];  // 9 KB, wave-private rows
  const int b = blockIdx.x;
  const size_t base = (size_t)b * 64 * 256;
  const __bf16* vwin = Vt + (size_t)b * 16384;  // this window's V^T, 32 KB
  const int tid = threadIdx.x;
  const int lane = tid & 63, wave = tid >> 6;
  const int l15 = lane & 15, quad = lane >> 4;

  // Q fragments direct from global (own 16 rows)
  bf16x8_t qf[8];
#pragma unroll
  for (int kc = 0; kc < 8; ++kc)
    qf[kc] = *reinterpret_cast<const bf16x8_t*>(
        &Qd[base + (wave * 16 + l15) * 256 + kc * 32 + quad * 8]);

  // S = (Q K^T)*scale + bias ; K fragments direct from global
  floatx4_t accs[4] = {};
#pragma unroll
  for (int ct = 0; ct < 4; ++ct)
#pragma unroll
    for (int kc = 0; kc < 8; ++kc) {
      bf16x8_t bfr = *reinterpret_cast<const bf16x8_t*>(
          &Kd[base + (ct * 16 + l15) * 256 + kc * 32 + quad * 8]);
      accs[ct] = MFMA16(qf[kc], bfr, accs[ct]);
    }

  // softmax per row (C-layout: row = wave*16 + quad*4 + g, col = ct*16 + l15)
  float p[4][4];
#pragma unroll
  for (int ct = 0; ct < 4; ++ct)
#pragma unroll
    for (int g = 0; g < 4; ++g) {
      int row = wave * 16 + quad * 4 + g;
      p[ct][g] = accs[ct][g] * 0.0625f + bias_ws[row * 64 + ct * 16 + l15];
    }
#pragma unroll
  for (int g = 0; g < 4; ++g) {
    float m = fmaxf(fmaxf(p[0][g], p[1][g]), fmaxf(p[2][g], p[3][g]));
#pragma unroll
    for (int off = 1; off < 16; off <<= 1) m = fmaxf(m, __shfl_xor(m, off, 64));
    float l = 0.f;
#pragma unroll
    for (int ct = 0; ct < 4; ++ct) {
      p[ct][g] = __expf(p[ct][g] - m);
      l += p[ct][g];
    }
#pragma unroll
    for (int off = 1; off < 16; off <<= 1) l += __shfl_xor(l, off, 64);
    float inv = 1.0f / l;
    int row = wave * 16 + quad * 4 + g;
#pragma unroll
    for (int ct = 0; ct < 4; ++ct)
      ldsP[row * VPITCH + ct * 16 + l15] = (__bf16)(p[ct][g] * inv);
  }
  // no __syncthreads: each wave reads only its own ldsP rows (lgkmcnt ordering)

  // O = P @ V~ : A = own P rows (LDS), B = V~ compact per-window tile
  floatx4_t acco[16] = {};
#pragma unroll
  for (int kc = 0; kc < 2; ++kc) {
    bf16x8_t af = *reinterpret_cast<const bf16x8_t*>(
        &ldsP[(wave * 16 + l15) * VPITCH + kc * 32 + quad * 8]);
#pragma unroll
    for (int ct = 0; ct < 16; ++ct) {
      int n = ct * 16 + l15;  // output dim d
      bf16x8_t bfr = *reinterpret_cast<const bf16x8_t*>(
          &vwin[n * 64 + kc * 32 + quad * 8]);
      acco[ct] = MFMA16(af, bfr, acco[ct]);
    }
  }
  // final write: out = acco + proj_b[col]  (fp32)
#pragma unroll
  for (int ct = 0; ct < 16; ++ct) {
    int col = ct * 16 + l15;
    float pbv = proj_b[col];
#pragma unroll
    for (int g = 0; g < 4; ++g) {
      int row = wave * 16 + quad * 4 + g;
      out[base + (size_t)row * 256 + col] = acco[ct][g] + pbv;
    }
  }
}

extern "C" void kernel_launch(void* const* d_in, const int* in_sizes, int n_in,
                              void* d_out, int out_size, void* d_ws, size_t ws_size,
                              hipStream_t stream) {
  const float* x = (const float*)d_in[0];
  const float* theta_max = (const float*)d_in[1];
  const float* qkv_w = (const float*)d_in[2];
  const float* qkv_b = (const float*)d_in[3];
  const float* proj_w = (const float*)d_in[4];
  const float* proj_b = (const float*)d_in[5];
  const float* a_p = (const float*)d_in[6];
  const float* b_p = (const float*)d_in[7];
  const float* a_r = (const float*)d_in[8];
  const float* b_r = (const float*)d_in[9];
  float* out = (float*)d_out;

  char* ws = (char*)d_ws;
  const size_t BUF = 67108864;  // 64 MiB: one (131072 x 256) bf16 buffer
  float* bias_ws = (float*)ws;                    // 16 KB
  float* btl = (float*)(ws + 16384);              // 1 KB (bt = Wp@bv)
  __bf16* wb = (__bf16*)(ws + 32768);             // 384 KB ([Wq;Wk;Wt])
  __bf16* Vt = (__bf16*)(ws + 1048576);           // 64 MB (per-window V~^T)
  __bf16* Qd = (__bf16*)(ws + 1048576 + BUF);     // 64 MB
  __bf16* Kd = (__bf16*)(ws + 1048576 + 2 * BUF); // 64 MB (~193 MiB total)

  hipLaunchKernelGGL(prep_kernel, dim3(336), dim3(256), 0, stream,
                     qkv_w, qkv_b, proj_w, theta_max, a_p, b_p, a_r, b_r,
                     wb, bias_ws, btl);
  hipLaunchKernelGGL(qkv_gemm_kernel, dim3(6144), dim3(256), 0, stream,
                     x, wb, qkv_b, btl, Qd, Kd, Vt);
  hipLaunchKernelGGL(attn_kernel, dim3(2048), dim3(256), 0, stream,
                     Qd, Kd, Vt, bias_ws, proj_b, out);
}

// Round 5
// 472.216 us; speedup vs baseline: 1.0376x; 1.0376x over previous
//
#include <hip/hip_runtime.h>
#include <hip/hip_bf16.h>

// WindowAttention B=2048, N=64, DIM=256, 1 head, scale=1/16.
// ALGEBRAIC FUSION: proj folded into V weights (Wt = Wp@Wv, bt = Wp@bv),
// so attention PV output IS the final output (+ proj_b).
// prep (blocked x->bf16, weights->bf16, Wt=Wp@Wv, bias table)
// -> qkv_gemm (async global->LDS bf16 A and B; XCD-swizzled grid;
//              V~ stored PER-WINDOW transposed [win][d][64], packed 8B stores)
// -> attn (barrier-free, direct-global Q/K + compact 32KB/window V~ tiles).

typedef __bf16 bf16x8_t __attribute__((ext_vector_type(8)));
typedef __bf16 bf16x4_t __attribute__((ext_vector_type(4)));
typedef float floatx4_t __attribute__((ext_vector_type(4)));

#define MFMA16(a, b, c) __builtin_amdgcn_mfma_f32_16x16x32_bf16(a, b, c, 0, 0, 0)
#define NTOK 131072  // 2048 windows * 64 tokens

__device__ __forceinline__ void gld_lds16(const void* g, void* l) {
  __builtin_amdgcn_global_load_lds(
      (const __attribute__((address_space(1))) unsigned int*)g,
      (__attribute__((address_space(3))) unsigned int*)l, 16, 0, 0);
}

__device__ __forceinline__ void cvt8(const float* src, __bf16* dst) {
  float4 f0 = reinterpret_cast<const float4*>(src)[0];
  float4 f1 = reinterpret_cast<const float4*>(src)[1];
  bf16x8_t h;
  h[0] = (__bf16)f0.x; h[1] = (__bf16)f0.y; h[2] = (__bf16)f0.z; h[3] = (__bf16)f0.w;
  h[4] = (__bf16)f1.x; h[5] = (__bf16)f1.y; h[6] = (__bf16)f1.z; h[7] = (__bf16)f1.w;
  *reinterpret_cast<bf16x8_t*>(dst) = h;
}

// ---- prep: blocked x->bf16 | Wq/Wk->bf16 | bias table | Wt=Wp@Wv + bt -----
// blk <2048: x cvt, 64KB contiguous per block (8 iters x 8KB)
// | <2112: qkv_w rows 0-511 | <2128: bias table | <2384: Wt row j + bt.
__global__ __launch_bounds__(256) void prep_kernel(
    const float* __restrict__ x, const float* __restrict__ qkv_w,
    const float* __restrict__ qkv_b, const float* __restrict__ proj_w,
    const float* __restrict__ theta_max,
    const float* __restrict__ a_p, const float* __restrict__ b_p,
    const float* __restrict__ a_r, const float* __restrict__ b_r,
    __bf16* __restrict__ xb, __bf16* __restrict__ wb,
    float* __restrict__ bias_ws, float* __restrict__ btl) {
  int blk = blockIdx.x, tid = threadIdx.x;
  if (blk < 2048) {
    // 16384 floats (64KB) contiguous per block
#pragma unroll
    for (int it = 0; it < 8; ++it) {
      size_t t = ((size_t)blk * 8 + it) * 2048 + (size_t)tid * 8;
      cvt8(&x[t], &xb[t]);
    }
  } else if (blk < 2112) {
    int t = (blk - 2048) * 256 + tid;  // rows 0..511 of qkv_w (Q,K weights)
    cvt8(&qkv_w[(size_t)t * 8], &wb[(size_t)t * 8]);
  } else if (blk < 2128) {
    int t = (blk - 2112) * 256 + tid;  // 0..4095
    int i = t >> 6, j = t & 63;
    int rad = (i >> 3) - (j >> 3), az = (i & 7) - (j & 7);
    int azm = ((az % 15) + 15) % 15;
    int rdm = ((rad % 15) + 15) % 15;
    float az_ang = (float)az * 0.09817477042468103f;  // 2*pi/64
    float tm = theta_max[j >> 3];                     // broadcasts over column j
    float r_ang = (float)rad * tm * (1.0f / 64.0f);
    bias_ws[t] = a_p[azm] * cosf(az_ang) + b_p[azm] * sinf(az_ang) +
                 a_r[rdm] * cosf(r_ang) + b_r[rdm] * sinf(r_ang);
  } else {
    // Wt[j,k] = sum_d proj_w[j,d] * qkv_w[512+d, k]  (fp32, -> bf16)
    int j = blk - 2128;  // 0..255
    int k = tid;
    float s = 0.f;
    for (int d = 0; d < 256; ++d)
      s += proj_w[j * 256 + d] * qkv_w[(size_t)(512 + d) * 256 + k];
    wb[(size_t)(512 + j) * 256 + k] = (__bf16)s;
    if (tid == 0) {
      float sb = 0.f;
      for (int d = 0; d < 256; ++d) sb += proj_w[j * 256 + d] * qkv_b[512 + d];
      btl[j] = sb;
    }
  }
}

// ---------------- QKV GEMM: (131072x256)bf16 @ (768x256)^T -----------------
// 128x128 tile, BK=64, async global->LDS (16B) for BOTH operands (round-1
// verified fast path), XOR-swizzled LDS. XCD-swizzled 1D grid (6144=8x768).
// Rows 512-767 of wb hold Wt -> emits projected V~ per-window transposed.
__global__ __launch_bounds__(256, 4) void qkv_gemm_kernel(
    const __bf16* __restrict__ xb, const __bf16* __restrict__ wb,
    const float* __restrict__ qkv_b, const float* __restrict__ btl,
    __bf16* __restrict__ Qd, __bf16* __restrict__ Kd, __bf16* __restrict__ Vt) {
  __shared__ __align__(16) __bf16 aT[128 * 64];  // 16 KB, swizzled chunks
  __shared__ __align__(16) __bf16 bT[128 * 64];
  const int tid = threadIdx.x;
  const int wg = blockIdx.x;
  const int id = (wg & 7) * 768 + (wg >> 3);  // 6144 = 8 XCDs * 768
  const int bm = id / 6, bn = id - bm * 6;
  const int lane = tid & 63, wave = tid >> 6;
  const int wm = (wave >> 1) * 64, wn = (wave & 1) * 64;
  const int l15 = lane & 15, quad = lane >> 4;

  floatx4_t acc[4][4] = {};

  for (int kt = 0; kt < 4; ++kt) {
#pragma unroll
    for (int i = 0; i < 4; ++i) {
      int L = tid + i * 256;               // chunk id 0..1023
      int row = L >> 3, sc = L & 7, c8 = sc ^ (row & 7);
      gld_lds16(&xb[(size_t)(bm * 128 + row) * 256 + kt * 64 + c8 * 8], &aT[L * 8]);
      gld_lds16(&wb[(size_t)(bn * 128 + row) * 256 + kt * 64 + c8 * 8], &bT[L * 8]);
    }
    __syncthreads();
#pragma unroll
    for (int kc = 0; kc < 2; ++kc) {
      bf16x8_t af[4], bfr[4];
#pragma unroll
      for (int r = 0; r < 4; ++r) {
        int row = wm + r * 16 + l15, c8 = kc * 4 + quad, sc = c8 ^ (row & 7);
        af[r] = *reinterpret_cast<const bf16x8_t*>(&aT[(row * 8 + sc) * 8]);
      }
#pragma unroll
      for (int c = 0; c < 4; ++c) {
        int row = wn + c * 16 + l15, c8 = kc * 4 + quad, sc = c8 ^ (row & 7);
        bfr[c] = *reinterpret_cast<const bf16x8_t*>(&bT[(row * 8 + sc) * 8]);
      }
#pragma unroll
      for (int r = 0; r < 4; ++r)
#pragma unroll
        for (int c = 0; c < 4; ++c) acc[r][c] = MFMA16(af[r], bfr[c], acc[r][c]);
    }
    __syncthreads();
  }
  // epilogue: n<256 -> Q row-major, <512 -> K row-major, else V~ per-window T
#pragma unroll
  for (int c = 0; c < 4; ++c) {
    int n = bn * 128 + wn + c * 16 + l15;
    float bias = (n < 512) ? qkv_b[n] : btl[n - 512];
    if (n < 512) {
      __bf16* outp = (n < 256) ? Qd : Kd;
      int d = n & 255;
#pragma unroll
      for (int r = 0; r < 4; ++r) {
        int m0 = bm * 128 + wm + r * 16 + quad * 4;
#pragma unroll
        for (int g = 0; g < 4; ++g)
          outp[(size_t)(m0 + g) * 256 + d] = (__bf16)(acc[r][c][g] + bias);
      }
    } else {
      int d = n - 512;
      int w = bm * 2 + (wave >> 1);  // window id (uniform per wave)
#pragma unroll
      for (int r = 0; r < 4; ++r) {
        int t = r * 16 + quad * 4;   // token base, multiple of 4 -> 8B aligned
        bf16x4_t pk;
#pragma unroll
        for (int g = 0; g < 4; ++g) pk[g] = (__bf16)(acc[r][c][g] + bias);
        *reinterpret_cast<bf16x4_t*>(&Vt[(size_t)w * 16384 + d * 64 + t]) = pk;
      }
    }
  }
}

// ------ attention (final): barrier-free, one block per window, fp32 out -----
// Q/K row-major per window; V~ per-window transposed 32KB tile (compact).
// ldsP is wave-private (each wave writes+reads only its own 16 rows).
// out = PV~ + proj_b  (proj folded into V~ weights).
#define VPITCH 72
__global__ __launch_bounds__(256, 4) void attn_kernel(
    const __bf16* __restrict__ Qd, const __bf16* __restrict__ Kd,
    const __bf16* __restrict__ Vt, const float* __restrict__ bias_ws,
    const float* __restrict__ proj_b, float* __restrict__ out) {
  __shared__ __align__(16) __bf16 ldsP[64 * VPITCH];  // 9 KB, wave-private rows
  const int b = blockIdx.x;
  const size_t base = (size_t)b * 64 * 256;
  const __bf16* vwin = Vt + (size_t)b * 16384;  // this window's V~^T, 32 KB
  const int tid = threadIdx.x;
  const int lane = tid & 63, wave = tid >> 6;
  const int l15 = lane & 15, quad = lane >> 4;

  // Q fragments direct from global (own 16 rows)
  bf16x8_t qf[8];
#pragma unroll
  for (int kc = 0; kc < 8; ++kc)
    qf[kc] = *reinterpret_cast<const bf16x8_t*>(
        &Qd[base + (wave * 16 + l15) * 256 + kc * 32 + quad * 8]);

  // S = (Q K^T)*scale + bias ; K fragments direct from global
  floatx4_t accs[4] = {};
#pragma unroll
  for (int ct = 0; ct < 4; ++ct)
#pragma unroll
    for (int kc = 0; kc < 8; ++kc) {
      bf16x8_t bfr = *reinterpret_cast<const bf16x8_t*>(
          &Kd[base + (ct * 16 + l15) * 256 + kc * 32 + quad * 8]);
      accs[ct] = MFMA16(qf[kc], bfr, accs[ct]);
    }

  // softmax per row (C-layout: row = wave*16 + quad*4 + g, col = ct*16 + l15)
  float p[4][4];
#pragma unroll
  for (int ct = 0; ct < 4; ++ct)
#pragma unroll
    for (int g = 0; g < 4; ++g) {
      int row = wave * 16 + quad * 4 + g;
      p[ct][g] = accs[ct][g] * 0.0625f + bias_ws[row * 64 + ct * 16 + l15];
    }
#pragma unroll
  for (int g = 0; g < 4; ++g) {
    float m = fmaxf(fmaxf(p[0][g], p[1][g]), fmaxf(p[2][g], p[3][g]));
#pragma unroll
    for (int off = 1; off < 16; off <<= 1) m = fmaxf(m, __shfl_xor(m, off, 64));
    float l = 0.f;
#pragma unroll
    for (int ct = 0; ct < 4; ++ct) {
      p[ct][g] = __expf(p[ct][g] - m);
      l += p[ct][g];
    }
#pragma unroll
    for (int off = 1; off < 16; off <<= 1) l += __shfl_xor(l, off, 64);
    float inv = 1.0f / l;
    int row = wave * 16 + quad * 4 + g;
#pragma unroll
    for (int ct = 0; ct < 4; ++ct)
      ldsP[row * VPITCH + ct * 16 + l15] = (__bf16)(p[ct][g] * inv);
  }
  // no __syncthreads: each wave reads only its own ldsP rows (lgkmcnt ordering)

  // O = P @ V~ : A = own P rows (LDS), B = V~ compact per-window tile
  floatx4_t acco[16] = {};
#pragma unroll
  for (int kc = 0; kc < 2; ++kc) {
    bf16x8_t af = *reinterpret_cast<const bf16x8_t*>(
        &ldsP[(wave * 16 + l15) * VPITCH + kc * 32 + quad * 8]);
#pragma unroll
    for (int ct = 0; ct < 16; ++ct) {
      int n = ct * 16 + l15;  // output dim d
      bf16x8_t bfr = *reinterpret_cast<const bf16x8_t*>(
          &vwin[n * 64 + kc * 32 + quad * 8]);
      acco[ct] = MFMA16(af, bfr, acco[ct]);
    }
  }
  // final write: out = acco + proj_b[col]  (fp32)
#pragma unroll
  for (int ct = 0; ct < 16; ++ct) {
    int col = ct * 16 + l15;
    float pbv = proj_b[col];
#pragma unroll
    for (int g = 0; g < 4; ++g) {
      int row = wave * 16 + quad * 4 + g;
      out[base + (size_t)row * 256 + col] = acco[ct][g] + pbv;
    }
  }
}

extern "C" void kernel_launch(void* const* d_in, const int* in_sizes, int n_in,
                              void* d_out, int out_size, void* d_ws, size_t ws_size,
                              hipStream_t stream) {
  const float* x = (const float*)d_in[0];
  const float* theta_max = (const float*)d_in[1];
  const float* qkv_w = (const float*)d_in[2];
  const float* qkv_b = (const float*)d_in[3];
  const float* proj_w = (const float*)d_in[4];
  const float* proj_b = (const float*)d_in[5];
  const float* a_p = (const float*)d_in[6];
  const float* b_p = (const float*)d_in[7];
  const float* a_r = (const float*)d_in[8];
  const float* b_r = (const float*)d_in[9];
  float* out = (float*)d_out;

  char* ws = (char*)d_ws;
  const size_t BUF = 67108864;  // 64 MiB: one (131072 x 256) bf16 buffer
  float* bias_ws = (float*)ws;                    // 16 KB
  float* btl = (float*)(ws + 16384);              // 1 KB (bt = Wp@bv)
  __bf16* wb = (__bf16*)(ws + 32768);             // 384 KB ([Wq;Wk;Wt])
  __bf16* xb = (__bf16*)(ws + 1048576);           // 64 MB
  __bf16* Vt = (__bf16*)(ws + 1048576 + BUF);     // 64 MB (per-window V~^T)
  __bf16* Qd = (__bf16*)(ws + 1048576 + 2 * BUF); // 64 MB
  __bf16* Kd = (__bf16*)(ws + 1048576 + 3 * BUF); // 64 MB (~257 MiB total,
                                                  //  confirmed fits, round 2)

  hipLaunchKernelGGL(prep_kernel, dim3(2384), dim3(256), 0, stream,
                     x, qkv_w, qkv_b, proj_w, theta_max, a_p, b_p, a_r, b_r,
                     xb, wb, bias_ws, btl);
  hipLaunchKernelGGL(qkv_gemm_kernel, dim3(6144), dim3(256), 0, stream,
                     xb, wb, qkv_b, btl, Qd, Kd, Vt);
  hipLaunchKernelGGL(attn_kernel, dim3(2048), dim3(256), 0, stream,
                     Qd, Kd, Vt, bias_ws, proj_b, out);
}

// Round 7
// 409.881 us; speedup vs baseline: 1.1954x; 1.1521x over previous
//
#include <hip/hip_runtime.h>
#include <hip/hip_bf16.h>

// WindowAttention B=2048, N=64, DIM=256, 1 head, scale=1/16.
// FULLY FUSED: one block per window computes QKV (MFMA, W from L2) -> S ->
// softmax -> PV -> out, entirely through LDS. Proj folded into V weights
// (Wt = Wp@Wv, bt = Wp@bv) so PV output IS the final output (+ proj_b).
// HBM traffic: read x (134 MB) + write out (134 MB) only.
// HARDENED SYNC vs r6: barrier after every QKV phase, full barrier after
// softmax, direct C-layout out store (r3-r5 verified), no LDS reuse.

typedef __bf16 bf16x8_t __attribute__((ext_vector_type(8)));
typedef __bf16 bf16x4_t __attribute__((ext_vector_type(4)));
typedef float floatx4_t __attribute__((ext_vector_type(4)));

#define MFMA16(a, b, c) __builtin_amdgcn_mfma_f32_16x16x32_bf16(a, b, c, 0, 0, 0)
#define VPITCH 72

__device__ __forceinline__ void cvt8(const float* src, __bf16* dst) {
  float4 f0 = reinterpret_cast<const float4*>(src)[0];
  float4 f1 = reinterpret_cast<const float4*>(src)[1];
  bf16x8_t h;
  h[0] = (__bf16)f0.x; h[1] = (__bf16)f0.y; h[2] = (__bf16)f0.z; h[3] = (__bf16)f0.w;
  h[4] = (__bf16)f1.x; h[5] = (__bf16)f1.y; h[6] = (__bf16)f1.z; h[7] = (__bf16)f1.w;
  *reinterpret_cast<bf16x8_t*>(dst) = h;
}

// ------------- prep: Wq/Wk->bf16, bias table, Wt=Wp@Wv + bt (tiny) ----------
__global__ __launch_bounds__(256) void prep_kernel(
    const float* __restrict__ qkv_w, const float* __restrict__ qkv_b,
    const float* __restrict__ proj_w, const float* __restrict__ theta_max,
    const float* __restrict__ a_p, const float* __restrict__ b_p,
    const float* __restrict__ a_r, const float* __restrict__ b_r,
    __bf16* __restrict__ wb, float* __restrict__ bias_ws,
    float* __restrict__ btl) {
  int blk = blockIdx.x, tid = threadIdx.x;
  if (blk < 64) {
    int t = blk * 256 + tid;  // rows 0..511 of qkv_w (Q,K weights)
    cvt8(&qkv_w[(size_t)t * 8], &wb[(size_t)t * 8]);
  } else if (blk < 80) {
    int t = (blk - 64) * 256 + tid;  // 0..4095
    int i = t >> 6, j = t & 63;
    int rad = (i >> 3) - (j >> 3), az = (i & 7) - (j & 7);
    int azm = ((az % 15) + 15) % 15;
    int rdm = ((rad % 15) + 15) % 15;
    float az_ang = (float)az * 0.09817477042468103f;  // 2*pi/64
    float tm = theta_max[j >> 3];                     // broadcasts over column j
    float r_ang = (float)rad * tm * (1.0f / 64.0f);
    bias_ws[t] = a_p[azm] * cosf(az_ang) + b_p[azm] * sinf(az_ang) +
                 a_r[rdm] * cosf(r_ang) + b_r[rdm] * sinf(r_ang);
  } else {
    // Wt[j,k] = sum_d proj_w[j,d] * qkv_w[512+d, k]  (fp32, -> bf16)
    int j = blk - 80;  // 0..255
    int k = tid;
    float s = 0.f;
    for (int d = 0; d < 256; ++d)
      s += proj_w[j * 256 + d] * qkv_w[(size_t)(512 + d) * 256 + k];
    wb[(size_t)(512 + j) * 256 + k] = (__bf16)s;
    if (tid == 0) {
      float sb = 0.f;
      for (int d = 0; d < 256; ++d) sb += proj_w[j * 256 + d] * qkv_b[512 + d];
      btl[j] = sb;
    }
  }
}

// --------------------- fused QKV + attention, one block per window ----------
// LDS tiles (unit-16B XOR-swizzled, unit u' = u ^ (row&7)):
//   ldsX: x window  [64 tok][256 d]   ldsQ/ldsK: [64 tok][256 d]
//   ldsV: V~^T      [256 d][64 tok]   ldsP: wave-private rows, pitch 72
// Phase p in {Q,K,V}: wave w computes all 64 tokens x cols [w*64,w*64+64),
// W rows read direct from global (L2-resident, disjoint per wave).
// Strict lifecycle: write phase -> __syncthreads -> read phase. No LDS reuse.
__global__ __launch_bounds__(256, 1) void fused_kernel(
    const float* __restrict__ x, const __bf16* __restrict__ wb,
    const float* __restrict__ qkv_b, const float* __restrict__ btl,
    const float* __restrict__ bias_ws, const float* __restrict__ proj_b,
    float* __restrict__ out) {
  __shared__ __align__(16) __bf16 ldsX[64 * 256];   // 32 KB
  __shared__ __align__(16) __bf16 ldsQ[64 * 256];   // 32 KB
  __shared__ __align__(16) __bf16 ldsK[64 * 256];   // 32 KB
  __shared__ __align__(16) __bf16 ldsV[256 * 64];   // 32 KB
  __shared__ __align__(16) __bf16 ldsP[64 * VPITCH];// 9 KB
  const int b = blockIdx.x;
  const size_t xbase = (size_t)b * 64 * 256;
  const int tid = threadIdx.x;
  const int lane = tid & 63, wave = tid >> 6;
  const int l15 = lane & 15, quad = lane >> 4;

  // ---- stage x window -> ldsX (bf16, swizzled) ----------------------------
  {
    int m = tid >> 2;       // 0..63 (row/token)
    int u0 = tid & 3;
#pragma unroll
    for (int i = 0; i < 8; ++i) {
      int u = u0 + i * 4;   // 16B-unit 0..31 (8 dims each)
      __bf16 tmp[8];
      cvt8(&x[xbase + m * 256 + u * 8], tmp);
      *reinterpret_cast<bf16x8_t*>(&ldsX[(m * 32 + (u ^ (m & 7))) * 8]) =
          *reinterpret_cast<bf16x8_t*>(tmp);
    }
  }
  __syncthreads();

  // ---- QKV phases (barrier after each) ------------------------------------
#pragma unroll 1
  for (int p = 0; p < 3; ++p) {
    floatx4_t acc[4][4] = {};
#pragma unroll
    for (int kc = 0; kc < 8; ++kc) {
      bf16x8_t af[4], bfr[4];
#pragma unroll
      for (int mt = 0; mt < 4; ++mt)
        af[mt] = *reinterpret_cast<const bf16x8_t*>(
            &ldsX[((mt * 16 + l15) * 32 + ((kc * 4 + quad) ^ (l15 & 7))) * 8]);
#pragma unroll
      for (int ct = 0; ct < 4; ++ct) {
        int n = p * 256 + wave * 64 + ct * 16 + l15;
        bfr[ct] = *reinterpret_cast<const bf16x8_t*>(
            &wb[(size_t)n * 256 + kc * 32 + quad * 8]);
      }
#pragma unroll
      for (int mt = 0; mt < 4; ++mt)
#pragma unroll
        for (int ct = 0; ct < 4; ++ct)
          acc[mt][ct] = MFMA16(af[mt], bfr[ct], acc[mt][ct]);
    }
    // epilogue: C-layout value at (token m = mt*16+quad*4+g, dim d)
    if (p < 2) {
      __bf16* dst = (p == 0) ? ldsQ : ldsK;
#pragma unroll
      for (int ct = 0; ct < 4; ++ct) {
        int d = wave * 64 + ct * 16 + l15;
        float bias = qkv_b[p * 256 + d];
        int u = d >> 3;
#pragma unroll
        for (int mt = 0; mt < 4; ++mt)
#pragma unroll
          for (int g = 0; g < 4; ++g) {
            int m = mt * 16 + quad * 4 + g;
            dst[(m * 32 + (u ^ (m & 7))) * 8 + (d & 7)] =
                (__bf16)(acc[mt][ct][g] + bias);
          }
      }
    } else {
      // V~^T tile [d][64 tok]: g-run = 4 consecutive tokens -> 8B packed
#pragma unroll
      for (int ct = 0; ct < 4; ++ct) {
        int d = wave * 64 + ct * 16 + l15;
        float bias = btl[d];
#pragma unroll
        for (int mt = 0; mt < 4; ++mt) {
          bf16x4_t pk;
#pragma unroll
          for (int g = 0; g < 4; ++g) pk[g] = (__bf16)(acc[mt][ct][g] + bias);
          int u = mt * 2 + (quad >> 1);  // token-unit = t/8
          *reinterpret_cast<bf16x4_t*>(
              &ldsV[(d * 8 + (u ^ (d & 7))) * 8 + (quad & 1) * 4]) = pk;
        }
      }
    }
    __syncthreads();  // phase output visible before anyone proceeds
  }

  // ---- S = (Q K^T)*scale + bias ------------------------------------------
  bf16x8_t qf[8];
#pragma unroll
  for (int kc = 0; kc < 8; ++kc)
    qf[kc] = *reinterpret_cast<const bf16x8_t*>(
        &ldsQ[((wave * 16 + l15) * 32 + ((kc * 4 + quad) ^ (l15 & 7))) * 8]);

  floatx4_t accs[4] = {};
#pragma unroll
  for (int ct = 0; ct < 4; ++ct)
#pragma unroll
    for (int kc = 0; kc < 8; ++kc) {
      bf16x8_t bfr = *reinterpret_cast<const bf16x8_t*>(
          &ldsK[((ct * 16 + l15) * 32 + ((kc * 4 + quad) ^ (l15 & 7))) * 8]);
      accs[ct] = MFMA16(qf[kc], bfr, accs[ct]);
    }

  // ---- softmax (row = wave*16 + quad*4 + g, col = ct*16 + l15) -------------
  float p[4][4];
#pragma unroll
  for (int ct = 0; ct < 4; ++ct)
#pragma unroll
    for (int g = 0; g < 4; ++g) {
      int row = wave * 16 + quad * 4 + g;
      p[ct][g] = accs[ct][g] * 0.0625f + bias_ws[row * 64 + ct * 16 + l15];
    }
#pragma unroll
  for (int g = 0; g < 4; ++g) {
    float m = fmaxf(fmaxf(p[0][g], p[1][g]), fmaxf(p[2][g], p[3][g]));
#pragma unroll
    for (int off = 1; off < 16; off <<= 1) m = fmaxf(m, __shfl_xor(m, off, 64));
    float l = 0.f;
#pragma unroll
    for (int ct = 0; ct < 4; ++ct) {
      p[ct][g] = __expf(p[ct][g] - m);
      l += p[ct][g];
    }
#pragma unroll
    for (int off = 1; off < 16; off <<= 1) l += __shfl_xor(l, off, 64);
    float inv = 1.0f / l;
    int row = wave * 16 + quad * 4 + g;
#pragma unroll
    for (int ct = 0; ct < 4; ++ct)
      ldsP[row * VPITCH + ct * 16 + l15] = (__bf16)(p[ct][g] * inv);
  }
  __syncthreads();  // P visible (full barrier; conservative)

  // ---- O = P @ V~ ----------------------------------------------------------
  floatx4_t acco[16] = {};
#pragma unroll
  for (int kc = 0; kc < 2; ++kc) {
    bf16x8_t af = *reinterpret_cast<const bf16x8_t*>(
        &ldsP[(wave * 16 + l15) * VPITCH + kc * 32 + quad * 8]);
#pragma unroll
    for (int ct = 0; ct < 16; ++ct) {
      int n = ct * 16 + l15;  // output dim d
      bf16x8_t bfr = *reinterpret_cast<const bf16x8_t*>(
          &ldsV[(n * 8 + ((kc * 4 + quad) ^ (n & 7))) * 8]);
      acco[ct] = MFMA16(af, bfr, acco[ct]);
    }
  }

  // ---- direct C-layout store (r3-r5 verified path) -------------------------
#pragma unroll
  for (int ct = 0; ct < 16; ++ct) {
    int col = ct * 16 + l15;
    float pbv = proj_b[col];
#pragma unroll
    for (int g = 0; g < 4; ++g) {
      int row = wave * 16 + quad * 4 + g;
      out[xbase + (size_t)row * 256 + col] = acco[ct][g] + pbv;
    }
  }
}

extern "C" void kernel_launch(void* const* d_in, const int* in_sizes, int n_in,
                              void* d_out, int out_size, void* d_ws, size_t ws_size,
                              hipStream_t stream) {
  const float* x = (const float*)d_in[0];
  const float* theta_max = (const float*)d_in[1];
  const float* qkv_w = (const float*)d_in[2];
  const float* qkv_b = (const float*)d_in[3];
  const float* proj_w = (const float*)d_in[4];
  const float* proj_b = (const float*)d_in[5];
  const float* a_p = (const float*)d_in[6];
  const float* b_p = (const float*)d_in[7];
  const float* a_r = (const float*)d_in[8];
  const float* b_r = (const float*)d_in[9];
  float* out = (float*)d_out;

  char* ws = (char*)d_ws;
  float* bias_ws = (float*)ws;                    // 16 KB
  float* btl = (float*)(ws + 16384);              // 1 KB (bt = Wp@bv)
  __bf16* wb = (__bf16*)(ws + 32768);             // 384 KB ([Wq;Wk;Wt])

  hipLaunchKernelGGL(prep_kernel, dim3(336), dim3(256), 0, stream,
                     qkv_w, qkv_b, proj_w, theta_max, a_p, b_p, a_r, b_r,
                     wb, bias_ws, btl);
  hipLaunchKernelGGL(fused_kernel, dim3(2048), dim3(256), 0, stream,
                     x, wb, qkv_b, btl, bias_ws, proj_b, out);
}

// Round 8
// 337.903 us; speedup vs baseline: 1.4500x; 1.2130x over previous
//
#include <hip/hip_runtime.h>
#include <hip/hip_bf16.h>

// WindowAttention B=2048, N=64, DIM=256, 1 head, scale=1/16.
// DOUBLE ALGEBRAIC FUSION, one block per window, 2 blocks/CU:
//  (1) proj folded into V:  Vt~ = X (Wp Wv)^T + Wp bv ; out = P Vt~ + bp.
//  (2) Q,K eliminated:      scale*q_i.k_j = x_i^T M x_j + c_j (+ softmax-
//      invariant terms, dropped exactly), M = scale Wq^T Wk,
//      c_j = (scale Wk^T bq) . x_j  -> G = X [M | u'], S^T = X G^T.
// Phases: stage X | G=X M_aug | S^T + transposed softmax -> P | V~ (over G)
//         | PV -> out.  LDS 75 KB -> 2 blocks/CU.

typedef __bf16 bf16x8_t __attribute__((ext_vector_type(8)));
typedef __bf16 bf16x4_t __attribute__((ext_vector_type(4)));
typedef float floatx4_t __attribute__((ext_vector_type(4)));

#define MFMA16(a, b, c) __builtin_amdgcn_mfma_f32_16x16x32_bf16(a, b, c, 0, 0, 0)
#define VPITCH 72

__device__ __forceinline__ void cvt8(const float* src, __bf16* dst) {
  float4 f0 = reinterpret_cast<const float4*>(src)[0];
  float4 f1 = reinterpret_cast<const float4*>(src)[1];
  bf16x8_t h;
  h[0] = (__bf16)f0.x; h[1] = (__bf16)f0.y; h[2] = (__bf16)f0.z; h[3] = (__bf16)f0.w;
  h[4] = (__bf16)f1.x; h[5] = (__bf16)f1.y; h[6] = (__bf16)f1.z; h[7] = (__bf16)f1.w;
  *reinterpret_cast<bf16x8_t*>(dst) = h;
}

// ---- prep: M'=scale Wq^T Wk (+u' col), Wt=Wp@Wv (+bt), bias table ----------
// blk<256: wbM row n | ==256: u' row + zero rows 257-271 | <513: Wt row j+btl
// | <529: bias table.
__global__ __launch_bounds__(256) void prep_kernel(
    const float* __restrict__ qkv_w, const float* __restrict__ qkv_b,
    const float* __restrict__ proj_w, const float* __restrict__ theta_max,
    const float* __restrict__ a_p, const float* __restrict__ b_p,
    const float* __restrict__ a_r, const float* __restrict__ b_r,
    __bf16* __restrict__ wbM, __bf16* __restrict__ wbV,
    float* __restrict__ bias_ws, float* __restrict__ btl) {
  int blk = blockIdx.x, tid = threadIdx.x;
  if (blk < 256) {
    // wbM[n][k] = M[k][n] = scale * sum_a Wq[a][k] * Wk[a][n]
    int n = blk, k = tid;
    float s = 0.f;
    for (int a = 0; a < 256; ++a)
      s += qkv_w[(size_t)a * 256 + k] * qkv_w[(size_t)(256 + a) * 256 + n];
    wbM[(size_t)n * 256 + k] = (__bf16)(s * 0.0625f);
  } else if (blk == 256) {
    // u'[k] = scale * sum_a Wk[a][k] * bq[a]; rows 257-271 zero
    int k = tid;
    float s = 0.f;
    for (int a = 0; a < 256; ++a)
      s += qkv_w[(size_t)(256 + a) * 256 + k] * qkv_b[a];
    wbM[(size_t)256 * 256 + k] = (__bf16)(s * 0.0625f);
    for (int r = 257; r < 272; ++r) wbM[(size_t)r * 256 + k] = (__bf16)0.f;
  } else if (blk < 513) {
    // Wt[j,k] = sum_d proj_w[j,d] * Wv[d,k]  (verified r3-r7)
    int j = blk - 257, k = tid;
    float s = 0.f;
    for (int d = 0; d < 256; ++d)
      s += proj_w[j * 256 + d] * qkv_w[(size_t)(512 + d) * 256 + k];
    wbV[(size_t)j * 256 + k] = (__bf16)s;
    if (tid == 0) {
      float sb = 0.f;
      for (int d = 0; d < 256; ++d) sb += proj_w[j * 256 + d] * qkv_b[512 + d];
      btl[j] = sb;
    }
  } else {
    int t = (blk - 513) * 256 + tid;  // 0..4095
    int i = t >> 6, j = t & 63;
    int rad = (i >> 3) - (j >> 3), az = (i & 7) - (j & 7);
    int azm = ((az % 15) + 15) % 15;
    int rdm = ((rad % 15) + 15) % 15;
    float az_ang = (float)az * 0.09817477042468103f;  // 2*pi/64
    float tm = theta_max[j >> 3];
    float r_ang = (float)rad * tm * (1.0f / 64.0f);
    bias_ws[t] = a_p[azm] * cosf(az_ang) + b_p[azm] * sinf(az_ang) +
                 a_r[rdm] * cosf(r_ang) + b_r[rdm] * sinf(r_ang);
  }
}

// --------------------- fused kernel, one block per window -------------------
// ldsX: X [64 tok][256 d], unit-swizzled (r7-verified staging/A-frag layout)
// ldsG: G [64 tok][272]    swz on units<32; REUSED as V~^T [256 d][64 tok]
// ldsP: P [64][VPITCH]     (r3-r7 verified)
__global__ __launch_bounds__(256, 2) void fused_kernel(
    const float* __restrict__ x, const __bf16* __restrict__ wbM,
    const __bf16* __restrict__ wbV, const float* __restrict__ btl,
    const float* __restrict__ bias_ws, const float* __restrict__ proj_b,
    float* __restrict__ out) {
  __shared__ __align__(16) __bf16 ldsX[64 * 32 * 8];   // 32 KB
  __shared__ __align__(16) __bf16 ldsG[64 * 34 * 8];   // 34 KB (G / V~^T)
  __shared__ __align__(16) __bf16 ldsP[64 * VPITCH];   // 9 KB
  const int b = blockIdx.x;
  const size_t xbase = (size_t)b * 64 * 256;
  const int tid = threadIdx.x;
  const int lane = tid & 63, wave = tid >> 6;
  const int l15 = lane & 15, quad = lane >> 4;

  // ---- stage x window -> ldsX (bf16, swizzled) [r7 verified] --------------
  {
    int m = tid >> 2;
    int u0 = tid & 3;
#pragma unroll
    for (int i = 0; i < 8; ++i) {
      int u = u0 + i * 4;
      __bf16 tmp[8];
      cvt8(&x[xbase + m * 256 + u * 8], tmp);
      *reinterpret_cast<bf16x8_t*>(&ldsX[(m * 32 + (u ^ (m & 7))) * 8]) =
          *reinterpret_cast<bf16x8_t*>(tmp);
    }
  }
  __syncthreads();

  // ---- G = X * [M | u'] : wave w computes col-tiles {w, w+4, w+8, w+12}
  //      (+ tile 16 = c-column on wave 0) ----------------------------------
  {
    floatx4_t accg[4][4] = {};
    floatx4_t accc[4] = {};
#pragma unroll
    for (int kc = 0; kc < 8; ++kc) {
      bf16x8_t af[4], bfr[4];
#pragma unroll
      for (int mt = 0; mt < 4; ++mt)
        af[mt] = *reinterpret_cast<const bf16x8_t*>(
            &ldsX[((mt * 16 + l15) * 32 + ((kc * 4 + quad) ^ (l15 & 7))) * 8]);
#pragma unroll
      for (int ct = 0; ct < 4; ++ct) {
        int n = (ct * 4 + wave) * 16 + l15;
        bfr[ct] = *reinterpret_cast<const bf16x8_t*>(
            &wbM[(size_t)n * 256 + kc * 32 + quad * 8]);
      }
#pragma unroll
      for (int mt = 0; mt < 4; ++mt)
#pragma unroll
        for (int ct = 0; ct < 4; ++ct)
          accg[mt][ct] = MFMA16(af[mt], bfr[ct], accg[mt][ct]);
      if (wave == 0) {
        bf16x8_t bc = *reinterpret_cast<const bf16x8_t*>(
            &wbM[(size_t)(256 + l15) * 256 + kc * 32 + quad * 8]);
#pragma unroll
        for (int mt = 0; mt < 4; ++mt) accc[mt] = MFMA16(af[mt], bc, accc[mt]);
      }
    }
    // write G (C-layout scalar, same pattern as r7 Q/K epilogue)
#pragma unroll
    for (int ct = 0; ct < 4; ++ct) {
      int n0 = (ct * 4 + wave) * 16 + l15;
      int u = n0 >> 3;
#pragma unroll
      for (int mt = 0; mt < 4; ++mt)
#pragma unroll
        for (int g = 0; g < 4; ++g) {
          int m = mt * 16 + quad * 4 + g;
          ldsG[(m * 34 + (u ^ (m & 7))) * 8 + (n0 & 7)] =
              (__bf16)accg[mt][ct][g];
        }
    }
    if (wave == 0) {  // c-column tile (units 32-33, unswizzled)
      int n0 = 256 + l15;
      int u = 32 + (l15 >> 3);
#pragma unroll
      for (int mt = 0; mt < 4; ++mt)
#pragma unroll
        for (int g = 0; g < 4; ++g) {
          int m = mt * 16 + quad * 4 + g;
          ldsG[(m * 34 + u) * 8 + (n0 & 7)] = (__bf16)accc[mt][g];
        }
    }
  }
  __syncthreads();

  // ---- S^T = X * G^T : wave w -> cols i = w*16+l15, rows j all 64 ----------
  floatx4_t accs[4] = {};
#pragma unroll
  for (int kc = 0; kc < 8; ++kc) {
    bf16x8_t af[4];
#pragma unroll
    for (int mt = 0; mt < 4; ++mt)
      af[mt] = *reinterpret_cast<const bf16x8_t*>(
          &ldsX[((mt * 16 + l15) * 32 + ((kc * 4 + quad) ^ (l15 & 7))) * 8]);
    int r = wave * 16 + l15;
    bf16x8_t bfr = *reinterpret_cast<const bf16x8_t*>(
        &ldsG[(r * 34 + ((kc * 4 + quad) ^ (r & 7))) * 8]);
#pragma unroll
    for (int mt = 0; mt < 4; ++mt) accs[mt] = MFMA16(af[mt], bfr, accs[mt]);
  }

  // ---- transposed softmax: lane owns col i = wave*16+l15, 16 j-values ------
  {
    const int i = wave * 16 + l15;
    float p[4][4];
    float mx = -1e30f;
#pragma unroll
    for (int mt = 0; mt < 4; ++mt)
#pragma unroll
      for (int g = 0; g < 4; ++g) {
        int j = mt * 16 + quad * 4 + g;
        float cj = (float)ldsG[(j * 34 + 32) * 8];  // c_j (col 256)
        p[mt][g] = accs[mt][g] + bias_ws[i * 64 + j] + cj;
        mx = fmaxf(mx, p[mt][g]);
      }
    mx = fmaxf(mx, __shfl_xor(mx, 16, 64));
    mx = fmaxf(mx, __shfl_xor(mx, 32, 64));
    float l = 0.f;
#pragma unroll
    for (int mt = 0; mt < 4; ++mt)
#pragma unroll
      for (int g = 0; g < 4; ++g) {
        p[mt][g] = __expf(p[mt][g] - mx);
        l += p[mt][g];
      }
    l += __shfl_xor(l, 16, 64);
    l += __shfl_xor(l, 32, 64);
    float inv = 1.0f / l;
#pragma unroll
    for (int mt = 0; mt < 4; ++mt)
#pragma unroll
      for (int g = 0; g < 4; ++g) {
        int j = mt * 16 + quad * 4 + g;
        ldsP[i * VPITCH + j] = (__bf16)(p[mt][g] * inv);
      }
  }
  __syncthreads();  // all c-reads/G-reads done; safe to overwrite ldsG

  // ---- V~ = X Wt^T + bt  -> V~^T tile over ldsG [r7 V-phase verbatim] -----
  {
    __bf16* ldsV = ldsG;
    floatx4_t accv[4][4] = {};
#pragma unroll
    for (int kc = 0; kc < 8; ++kc) {
      bf16x8_t af[4], bfr[4];
#pragma unroll
      for (int mt = 0; mt < 4; ++mt)
        af[mt] = *reinterpret_cast<const bf16x8_t*>(
            &ldsX[((mt * 16 + l15) * 32 + ((kc * 4 + quad) ^ (l15 & 7))) * 8]);
#pragma unroll
      for (int ct = 0; ct < 4; ++ct) {
        int n = wave * 64 + ct * 16 + l15;
        bfr[ct] = *reinterpret_cast<const bf16x8_t*>(
            &wbV[(size_t)n * 256 + kc * 32 + quad * 8]);
      }
#pragma unroll
      for (int mt = 0; mt < 4; ++mt)
#pragma unroll
        for (int ct = 0; ct < 4; ++ct)
          accv[mt][ct] = MFMA16(af[mt], bfr[ct], accv[mt][ct]);
    }
#pragma unroll
    for (int ct = 0; ct < 4; ++ct) {
      int d = wave * 64 + ct * 16 + l15;
      float bias = btl[d];
#pragma unroll
      for (int mt = 0; mt < 4; ++mt) {
        bf16x4_t pk;
#pragma unroll
        for (int g = 0; g < 4; ++g) pk[g] = (__bf16)(accv[mt][ct][g] + bias);
        int u = mt * 2 + (quad >> 1);
        *reinterpret_cast<bf16x4_t*>(
            &ldsV[(d * 8 + (u ^ (d & 7))) * 8 + (quad & 1) * 4]) = pk;
      }
    }
  }
  __syncthreads();

  // ---- O = P @ V~ + bp  [r7 verbatim] -------------------------------------
  {
    const __bf16* ldsV = ldsG;
    floatx4_t acco[16] = {};
#pragma unroll
    for (int kc = 0; kc < 2; ++kc) {
      bf16x8_t af = *reinterpret_cast<const bf16x8_t*>(
          &ldsP[(wave * 16 + l15) * VPITCH + kc * 32 + quad * 8]);
#pragma unroll
      for (int ct = 0; ct < 16; ++ct) {
        int n = ct * 16 + l15;
        bf16x8_t bfr = *reinterpret_cast<const bf16x8_t*>(
            &ldsV[(n * 8 + ((kc * 4 + quad) ^ (n & 7))) * 8]);
        acco[ct] = MFMA16(af, bfr, acco[ct]);
      }
    }
#pragma unroll
    for (int ct = 0; ct < 16; ++ct) {
      int col = ct * 16 + l15;
      float pbv = proj_b[col];
#pragma unroll
      for (int g = 0; g < 4; ++g) {
        int row = wave * 16 + quad * 4 + g;
        out[xbase + (size_t)row * 256 + col] = acco[ct][g] + pbv;
      }
    }
  }
}

extern "C" void kernel_launch(void* const* d_in, const int* in_sizes, int n_in,
                              void* d_out, int out_size, void* d_ws, size_t ws_size,
                              hipStream_t stream) {
  const float* x = (const float*)d_in[0];
  const float* theta_max = (const float*)d_in[1];
  const float* qkv_w = (const float*)d_in[2];
  const float* qkv_b = (const float*)d_in[3];
  const float* proj_w = (const float*)d_in[4];
  const float* proj_b = (const float*)d_in[5];
  const float* a_p = (const float*)d_in[6];
  const float* b_p = (const float*)d_in[7];
  const float* a_r = (const float*)d_in[8];
  const float* b_r = (const float*)d_in[9];
  float* out = (float*)d_out;

  char* ws = (char*)d_ws;
  float* bias_ws = (float*)ws;                    // 16 KB
  float* btl = (float*)(ws + 16384);              // 1 KB
  __bf16* wbM = (__bf16*)(ws + 32768);            // 139.3 KB (272x256)
  __bf16* wbV = (__bf16*)(ws + 172032);           // 128 KB  (256x256)

  hipLaunchKernelGGL(prep_kernel, dim3(529), dim3(256), 0, stream,
                     qkv_w, qkv_b, proj_w, theta_max, a_p, b_p, a_r, b_r,
                     wbM, wbV, bias_ws, btl);
  hipLaunchKernelGGL(fused_kernel, dim3(2048), dim3(256), 0, stream,
                     x, wbM, wbV, btl, bias_ws, proj_b, out);
}

// Round 9
// 328.065 us; speedup vs baseline: 1.4935x; 1.0300x over previous
//
#include <hip/hip_runtime.h>
#include <hip/hip_bf16.h>

// WindowAttention B=2048, N=64, DIM=256, 1 head, scale=1/16.
// DOUBLE ALGEBRAIC FUSION, one block per window, 2 blocks/CU:
//  (1) proj folded into V:  Vt~ = X (Wp Wv)^T + Wp bv ; out = P Vt~ + bp.
//  (2) Q,K eliminated:      scale*q_i.k_j = x_i^T M x_j + c_j (+ softmax-
//      invariant terms, dropped exactly), M = scale Wq^T Wk,
//      c_j = (scale Wk^T bq) . x_j  -> G = X [M | u'], S^T = X G^T.
// r9: T14 issue-early weight prefetch (wbM before X-stage, wbV under softmax),
//     float4 bias loads, setprio around MFMA clusters.

typedef __bf16 bf16x8_t __attribute__((ext_vector_type(8)));
typedef __bf16 bf16x4_t __attribute__((ext_vector_type(4)));
typedef float floatx4_t __attribute__((ext_vector_type(4)));

#define MFMA16(a, b, c) __builtin_amdgcn_mfma_f32_16x16x32_bf16(a, b, c, 0, 0, 0)
#define VPITCH 72

__device__ __forceinline__ void cvt8(const float* src, __bf16* dst) {
  float4 f0 = reinterpret_cast<const float4*>(src)[0];
  float4 f1 = reinterpret_cast<const float4*>(src)[1];
  bf16x8_t h;
  h[0] = (__bf16)f0.x; h[1] = (__bf16)f0.y; h[2] = (__bf16)f0.z; h[3] = (__bf16)f0.w;
  h[4] = (__bf16)f1.x; h[5] = (__bf16)f1.y; h[6] = (__bf16)f1.z; h[7] = (__bf16)f1.w;
  *reinterpret_cast<bf16x8_t*>(dst) = h;
}

// ---- prep: M'=scale Wq^T Wk (+u' col), Wt=Wp@Wv (+bt), bias table ----------
__global__ __launch_bounds__(256) void prep_kernel(
    const float* __restrict__ qkv_w, const float* __restrict__ qkv_b,
    const float* __restrict__ proj_w, const float* __restrict__ theta_max,
    const float* __restrict__ a_p, const float* __restrict__ b_p,
    const float* __restrict__ a_r, const float* __restrict__ b_r,
    __bf16* __restrict__ wbM, __bf16* __restrict__ wbV,
    float* __restrict__ bias_ws, float* __restrict__ btl) {
  int blk = blockIdx.x, tid = threadIdx.x;
  if (blk < 256) {
    // wbM[n][k] = M[k][n] = scale * sum_a Wq[a][k] * Wk[a][n]
    int n = blk, k = tid;
    float s = 0.f;
    for (int a = 0; a < 256; ++a)
      s += qkv_w[(size_t)a * 256 + k] * qkv_w[(size_t)(256 + a) * 256 + n];
    wbM[(size_t)n * 256 + k] = (__bf16)(s * 0.0625f);
  } else if (blk == 256) {
    // u'[k] = scale * sum_a Wk[a][k] * bq[a]; rows 257-271 zero
    int k = tid;
    float s = 0.f;
    for (int a = 0; a < 256; ++a)
      s += qkv_w[(size_t)(256 + a) * 256 + k] * qkv_b[a];
    wbM[(size_t)256 * 256 + k] = (__bf16)(s * 0.0625f);
    for (int r = 257; r < 272; ++r) wbM[(size_t)r * 256 + k] = (__bf16)0.f;
  } else if (blk < 513) {
    // Wt[j,k] = sum_d proj_w[j,d] * Wv[d,k]
    int j = blk - 257, k = tid;
    float s = 0.f;
    for (int d = 0; d < 256; ++d)
      s += proj_w[j * 256 + d] * qkv_w[(size_t)(512 + d) * 256 + k];
    wbV[(size_t)j * 256 + k] = (__bf16)s;
    if (tid == 0) {
      float sb = 0.f;
      for (int d = 0; d < 256; ++d) sb += proj_w[j * 256 + d] * qkv_b[512 + d];
      btl[j] = sb;
    }
  } else {
    int t = (blk - 513) * 256 + tid;  // 0..4095
    int i = t >> 6, j = t & 63;
    int rad = (i >> 3) - (j >> 3), az = (i & 7) - (j & 7);
    int azm = ((az % 15) + 15) % 15;
    int rdm = ((rad % 15) + 15) % 15;
    float az_ang = (float)az * 0.09817477042468103f;  // 2*pi/64
    float tm = theta_max[j >> 3];
    float r_ang = (float)rad * tm * (1.0f / 64.0f);
    bias_ws[t] = a_p[azm] * cosf(az_ang) + b_p[azm] * sinf(az_ang) +
                 a_r[rdm] * cosf(r_ang) + b_r[rdm] * sinf(r_ang);
  }
}

// --------------------- fused kernel, one block per window -------------------
__global__ __launch_bounds__(256, 2) void fused_kernel(
    const float* __restrict__ x, const __bf16* __restrict__ wbM,
    const __bf16* __restrict__ wbV, const float* __restrict__ btl,
    const float* __restrict__ bias_ws, const float* __restrict__ proj_b,
    float* __restrict__ out) {
  __shared__ __align__(16) __bf16 ldsX[64 * 32 * 8];   // 32 KB
  __shared__ __align__(16) __bf16 ldsG[64 * 34 * 8];   // 34 KB (G / V~^T)
  __shared__ __align__(16) __bf16 ldsP[64 * VPITCH];   // 9 KB
  const int b = blockIdx.x;
  const size_t xbase = (size_t)b * 64 * 256;
  const int tid = threadIdx.x;
  const int lane = tid & 63, wave = tid >> 6;
  const int l15 = lane & 15, quad = lane >> 4;

  // ---- T14: issue wbM B-frag loads (kc 0-3) BEFORE X staging --------------
  bf16x8_t wm0[4][4];  // [kc][ct]
#pragma unroll
  for (int kc = 0; kc < 4; ++kc)
#pragma unroll
    for (int ct = 0; ct < 4; ++ct) {
      int n = (ct * 4 + wave) * 16 + l15;
      wm0[kc][ct] = *reinterpret_cast<const bf16x8_t*>(
          &wbM[(size_t)n * 256 + kc * 32 + quad * 8]);
    }

  // ---- stage x window -> ldsX (bf16, swizzled) [r7/r8 verified] -----------
  {
    int m = tid >> 2;
    int u0 = tid & 3;
#pragma unroll
    for (int i = 0; i < 8; ++i) {
      int u = u0 + i * 4;
      __bf16 tmp[8];
      cvt8(&x[xbase + m * 256 + u * 8], tmp);
      *reinterpret_cast<bf16x8_t*>(&ldsX[(m * 32 + (u ^ (m & 7))) * 8]) =
          *reinterpret_cast<bf16x8_t*>(tmp);
    }
  }
  __syncthreads();

  // ---- G = X * [M | u'] ---------------------------------------------------
  bf16x8_t wv0[4][4];  // wbV prefetch, issued after the G MFMA loop
  {
    floatx4_t accg[4][4] = {};
    floatx4_t accc[4] = {};
    __builtin_amdgcn_s_setprio(1);
#pragma unroll
    for (int kc = 0; kc < 8; ++kc) {
      bf16x8_t af[4], bfr[4];
#pragma unroll
      for (int mt = 0; mt < 4; ++mt)
        af[mt] = *reinterpret_cast<const bf16x8_t*>(
            &ldsX[((mt * 16 + l15) * 32 + ((kc * 4 + quad) ^ (l15 & 7))) * 8]);
#pragma unroll
      for (int ct = 0; ct < 4; ++ct) {
        int n = (ct * 4 + wave) * 16 + l15;
        bfr[ct] = (kc < 4) ? wm0[kc][ct]
                           : *reinterpret_cast<const bf16x8_t*>(
                                 &wbM[(size_t)n * 256 + kc * 32 + quad * 8]);
      }
#pragma unroll
      for (int mt = 0; mt < 4; ++mt)
#pragma unroll
        for (int ct = 0; ct < 4; ++ct)
          accg[mt][ct] = MFMA16(af[mt], bfr[ct], accg[mt][ct]);
      if (wave == 0) {
        bf16x8_t bc = *reinterpret_cast<const bf16x8_t*>(
            &wbM[(size_t)(256 + l15) * 256 + kc * 32 + quad * 8]);
#pragma unroll
        for (int mt = 0; mt < 4; ++mt) accc[mt] = MFMA16(af[mt], bc, accc[mt]);
      }
    }
    __builtin_amdgcn_s_setprio(0);

    // ---- T14: issue wbV loads now; consumed in V~ phase after 2 barriers --
#pragma unroll
    for (int kc = 0; kc < 4; ++kc)
#pragma unroll
      for (int ct = 0; ct < 4; ++ct) {
        int n = wave * 64 + ct * 16 + l15;
        wv0[kc][ct] = *reinterpret_cast<const bf16x8_t*>(
            &wbV[(size_t)n * 256 + kc * 32 + quad * 8]);
      }

    // write G (C-layout scalar) [r8 verified]
#pragma unroll
    for (int ct = 0; ct < 4; ++ct) {
      int n0 = (ct * 4 + wave) * 16 + l15;
      int u = n0 >> 3;
#pragma unroll
      for (int mt = 0; mt < 4; ++mt)
#pragma unroll
        for (int g = 0; g < 4; ++g) {
          int m = mt * 16 + quad * 4 + g;
          ldsG[(m * 34 + (u ^ (m & 7))) * 8 + (n0 & 7)] =
              (__bf16)accg[mt][ct][g];
        }
    }
    if (wave == 0) {  // c-column tile (units 32-33, unswizzled)
      int n0 = 256 + l15;
      int u = 32 + (l15 >> 3);
#pragma unroll
      for (int mt = 0; mt < 4; ++mt)
#pragma unroll
        for (int g = 0; g < 4; ++g) {
          int m = mt * 16 + quad * 4 + g;
          ldsG[(m * 34 + u) * 8 + (n0 & 7)] = (__bf16)accc[mt][g];
        }
    }
  }
  __syncthreads();

  // ---- S^T = X * G^T [r8 verified] ----------------------------------------
  floatx4_t accs[4] = {};
  __builtin_amdgcn_s_setprio(1);
#pragma unroll
  for (int kc = 0; kc < 8; ++kc) {
    bf16x8_t af[4];
#pragma unroll
    for (int mt = 0; mt < 4; ++mt)
      af[mt] = *reinterpret_cast<const bf16x8_t*>(
          &ldsX[((mt * 16 + l15) * 32 + ((kc * 4 + quad) ^ (l15 & 7))) * 8]);
    int r = wave * 16 + l15;
    bf16x8_t bfr = *reinterpret_cast<const bf16x8_t*>(
        &ldsG[(r * 34 + ((kc * 4 + quad) ^ (r & 7))) * 8]);
#pragma unroll
    for (int mt = 0; mt < 4; ++mt) accs[mt] = MFMA16(af[mt], bfr, accs[mt]);
  }
  __builtin_amdgcn_s_setprio(0);

  // ---- transposed softmax: lane owns col i = wave*16+l15 ------------------
  {
    const int i = wave * 16 + l15;
    float p[4][4];
    float mx = -1e30f;
#pragma unroll
    for (int mt = 0; mt < 4; ++mt) {
      float4 bb = *reinterpret_cast<const float4*>(
          &bias_ws[i * 64 + mt * 16 + quad * 4]);
#pragma unroll
      for (int g = 0; g < 4; ++g) {
        int j = mt * 16 + quad * 4 + g;
        float cj = (float)ldsG[(j * 34 + 32) * 8];  // c_j (col 256)
        p[mt][g] = accs[mt][g] + ((const float*)&bb)[g] + cj;
        mx = fmaxf(mx, p[mt][g]);
      }
    }
    mx = fmaxf(mx, __shfl_xor(mx, 16, 64));
    mx = fmaxf(mx, __shfl_xor(mx, 32, 64));
    float l = 0.f;
#pragma unroll
    for (int mt = 0; mt < 4; ++mt)
#pragma unroll
      for (int g = 0; g < 4; ++g) {
        p[mt][g] = __expf(p[mt][g] - mx);
        l += p[mt][g];
      }
    l += __shfl_xor(l, 16, 64);
    l += __shfl_xor(l, 32, 64);
    float inv = 1.0f / l;
#pragma unroll
    for (int mt = 0; mt < 4; ++mt)
#pragma unroll
      for (int g = 0; g < 4; ++g) {
        int j = mt * 16 + quad * 4 + g;
        ldsP[i * VPITCH + j] = (__bf16)(p[mt][g] * inv);
      }
  }
  __syncthreads();  // all G-reads done; safe to overwrite ldsG

  // ---- V~ = X Wt^T + bt -> V~^T tile over ldsG [r8 verified] --------------
  {
    __bf16* ldsV = ldsG;
    floatx4_t accv[4][4] = {};
    __builtin_amdgcn_s_setprio(1);
#pragma unroll
    for (int kc = 0; kc < 8; ++kc) {
      bf16x8_t af[4], bfr[4];
#pragma unroll
      for (int mt = 0; mt < 4; ++mt)
        af[mt] = *reinterpret_cast<const bf16x8_t*>(
            &ldsX[((mt * 16 + l15) * 32 + ((kc * 4 + quad) ^ (l15 & 7))) * 8]);
#pragma unroll
      for (int ct = 0; ct < 4; ++ct) {
        int n = wave * 64 + ct * 16 + l15;
        bfr[ct] = (kc < 4) ? wv0[kc][ct]
                           : *reinterpret_cast<const bf16x8_t*>(
                                 &wbV[(size_t)n * 256 + kc * 32 + quad * 8]);
      }
#pragma unroll
      for (int mt = 0; mt < 4; ++mt)
#pragma unroll
        for (int ct = 0; ct < 4; ++ct)
          accv[mt][ct] = MFMA16(af[mt], bfr[ct], accv[mt][ct]);
    }
    __builtin_amdgcn_s_setprio(0);
#pragma unroll
    for (int ct = 0; ct < 4; ++ct) {
      int d = wave * 64 + ct * 16 + l15;
      float bias = btl[d];
#pragma unroll
      for (int mt = 0; mt < 4; ++mt) {
        bf16x4_t pk;
#pragma unroll
        for (int g = 0; g < 4; ++g) pk[g] = (__bf16)(accv[mt][ct][g] + bias);
        int u = mt * 2 + (quad >> 1);
        *reinterpret_cast<bf16x4_t*>(
            &ldsV[(d * 8 + (u ^ (d & 7))) * 8 + (quad & 1) * 4]) = pk;
      }
    }
  }
  __syncthreads();

  // ---- O = P @ V~ + bp [r8 verified] --------------------------------------
  {
    const __bf16* ldsV = ldsG;
    floatx4_t acco[16] = {};
    __builtin_amdgcn_s_setprio(1);
#pragma unroll
    for (int kc = 0; kc < 2; ++kc) {
      bf16x8_t af = *reinterpret_cast<const bf16x8_t*>(
          &ldsP[(wave * 16 + l15) * VPITCH + kc * 32 + quad * 8]);
#pragma unroll
      for (int ct = 0; ct < 16; ++ct) {
        int n = ct * 16 + l15;
        bf16x8_t bfr = *reinterpret_cast<const bf16x8_t*>(
            &ldsV[(n * 8 + ((kc * 4 + quad) ^ (n & 7))) * 8]);
        acco[ct] = MFMA16(af, bfr, acco[ct]);
      }
    }
    __builtin_amdgcn_s_setprio(0);
#pragma unroll
    for (int ct = 0; ct < 16; ++ct) {
      int col = ct * 16 + l15;
      float pbv = proj_b[col];
#pragma unroll
      for (int g = 0; g < 4; ++g) {
        int row = wave * 16 + quad * 4 + g;
        out[xbase + (size_t)row * 256 + col] = acco[ct][g] + pbv;
      }
    }
  }
}

extern "C" void kernel_launch(void* const* d_in, const int* in_sizes, int n_in,
                              void* d_out, int out_size, void* d_ws, size_t ws_size,
                              hipStream_t stream) {
  const float* x = (const float*)d_in[0];
  const float* theta_max = (const float*)d_in[1];
  const float* qkv_w = (const float*)d_in[2];
  const float* qkv_b = (const float*)d_in[3];
  const float* proj_w = (const float*)d_in[4];
  const float* proj_b = (const float*)d_in[5];
  const float* a_p = (const float*)d_in[6];
  const float* b_p = (const float*)d_in[7];
  const float* a_r = (const float*)d_in[8];
  const float* b_r = (const float*)d_in[9];
  float* out = (float*)d_out;

  char* ws = (char*)d_ws;
  float* bias_ws = (float*)ws;                    // 16 KB
  float* btl = (float*)(ws + 16384);              // 1 KB
  __bf16* wbM = (__bf16*)(ws + 32768);            // 139.3 KB (272x256)
  __bf16* wbV = (__bf16*)(ws + 172032);           // 128 KB  (256x256)

  hipLaunchKernelGGL(prep_kernel, dim3(529), dim3(256), 0, stream,
                     qkv_w, qkv_b, proj_w, theta_max, a_p, b_p, a_r, b_r,
                     wbM, wbV, bias_ws, btl);
  hipLaunchKernelGGL(fused_kernel, dim3(2048), dim3(256), 0, stream,
                     x, wbM, wbV, btl, bias_ws, proj_b, out);
}